// Round 6
// baseline (222.450 us; speedup 1.0000x reference)
//
#include <hip/hip_runtime.h>
#include <hip/hip_bf16.h>

typedef _Float16 half8 __attribute__((ext_vector_type(8)));
typedef float    floatx4 __attribute__((ext_vector_type(4)));

#define WSCALE      4096.0f
#define WSCALE_INV  (1.0f/(4096.0f*4096.0f))

// ws layout (float offsets)
#define S0_OFF   0      // 256 floats  (1,16,4,4)
#define S1_OFF   256    // 4096        (16,16,4,4)
#define S2_OFF   4352   // 4096
#define S3_OFF   8448   // 256         (16,1,4,4)
#define T1_OFF   8704   // 4096        (16,16,16)
#define T2_OFF   12800  // 65536       (16,64,64)
#define WF16_OFF 78336  // 65536 _Float16, fragment-major; 16B-aligned

// ---- Fused W-prep: all 4 contraction stages in one single-block kernel ----
// Stage RAW through global ws; __threadfence() (L1 invalidate) + barrier
// between stages makes same-block global RAW safe.
__global__ __launch_bounds__(1024)
void mpo_prep(const float* __restrict__ w, float* __restrict__ ws,
              _Float16* __restrict__ Wf) {
    const int tid = threadIdx.x;

    // Stage A: pair-contract adjacent cores -> 4 supercores (l,r,4,4)
    for (int idx = tid; idx < 8704; idx += 1024) {
        int p, base, r, outoff;
        if      (idx < 256)  { p = 0; base = 0;    r = 16; outoff = S0_OFF; }
        else if (idx < 4352) { p = 1; base = 256;  r = 16; outoff = S1_OFF; }
        else if (idx < 8448) { p = 2; base = 4352; r = 16; outoff = S2_OFF; }
        else                 { p = 3; base = 8448; r = 1;  outoff = S3_OFF; }
        int li = idx - base;
        int mm = li & 3, kk = (li >> 2) & 3, ac = li >> 4;
        int c = ac % r, a = ac / r;
        int k1 = kk >> 1, k2 = kk & 1, m1 = mm >> 1, m2 = mm & 1;
        const int coreoff[8] = {0, 64, 1088, 2112, 3136, 4160, 5184, 6208};
        const float* A = w + coreoff[2 * p];       // (l,16,2,2)
        const float* B = w + coreoff[2 * p + 1];   // (16,r,2,2)
        float s = 0.f;
        for (int b = 0; b < 16; ++b)
            s += A[((a * 16 + b) * 2 + k1) * 2 + m1] * B[((b * r + c) * 2 + k2) * 2 + m2];
        ws[outoff + li] = s;
    }
    __threadfence(); __syncthreads();

    // Stage B: T1(16,16,16) = S0(16,4,4) x S1(16,16,4,4)
    for (int idx = tid; idx < 4096; idx += 1024) {
        const float* T = ws + S0_OFF; const float* S = ws + S1_OFF;
        int J4 = idx % 16; int t = idx / 16; int I4 = t % 16; int b = t / 16;
        int I = I4 >> 2, k = I4 & 3, J = J4 >> 2, m = J4 & 3;
        float s = 0.f;
        for (int a = 0; a < 16; ++a)
            s += T[(a * 4 + I) * 4 + J] * S[((a * 16 + b) * 4 + k) * 4 + m];
        ws[T1_OFF + idx] = s;
    }
    __threadfence(); __syncthreads();

    // Stage C: T2(16,64,64) = T1(16,16,16) x S2(16,16,4,4)
    for (int idx = tid; idx < 65536; idx += 1024) {
        const float* T = ws + T1_OFF; const float* S = ws + S2_OFF;
        int J4 = idx % 64; int t = idx / 64; int I4 = t % 64; int b = t / 64;
        int I = I4 >> 2, k = I4 & 3, J = J4 >> 2, m = J4 & 3;
        float s = 0.f;
        for (int a = 0; a < 16; ++a)
            s += T[(a * 16 + I) * 16 + J] * S[((a * 16 + b) * 4 + k) * 4 + m];
        ws[T2_OFF + idx] = s;
    }
    __threadfence(); __syncthreads();

    // Stage D: final contraction + scale + fp16 + FRAGMENT-MAJOR layout.
    // W[k=I4][col=J4]; strip n=col>>4, lrow=col&15, kk=k>>5, g=(k>>3)&3, j=k&7.
    for (int idx = tid; idx < 65536; idx += 1024) {
        const float* T = ws + T2_OFF; const float* S = ws + S3_OFF;
        int J4 = idx & 255; int I4 = idx >> 8;            // col, k
        int I = I4 >> 2, k = I4 & 3, J = J4 >> 2, m = J4 & 3;
        float s = 0.f;
        for (int a = 0; a < 16; ++a)
            s += T[(a * 64 + I) * 64 + J] * S[(a * 4 + k) * 4 + m];
        int n = J4 >> 4, lr = J4 & 15, kk = I4 >> 5, gg = (I4 >> 3) & 3, j = I4 & 7;
        Wf[(((n * 8 + kk) * 64) + gg * 16 + lr) * 8 + j] = (_Float16)(s * WSCALE);
    }
}

// ---- Main fused kernel ----
// 256 blocks x 512 threads (8 waves, 2/SIMD, VGPR cap 256). All of W (128 KB)
// + dk (1 KB) in LDS; one barrier. 16 rows/wave x 8 passes with CROSS-PASS
// x prefetch: next pass's 8 fragments (lo/hi[8], 64 VGPR) are issued before
// the n-loop and converted after it -> HBM streams continuously under compute.
// dk reads come from LDS so the n-loop has NO vmcnt waits.
__global__ __launch_bounds__(512, 2)
void mpo_main(const float* __restrict__ x, const _Float16* __restrict__ Wf,
              const float* __restrict__ dk, const float* __restrict__ bias,
              float* __restrict__ out) {
    extern __shared__ _Float16 Wl[];                       // 65536 halves + 256 floats
    float* dkL = reinterpret_cast<float*>(Wl + 65536);

    const int tid  = threadIdx.x;
    const int lane = tid & 63;
    const int wave = tid >> 6;        // 0..7
    const int lrow = lane & 15;       // A row / C col within tile
    const int g    = lane >> 4;       // k-group

    const long blockbase = (long)blockIdx.x * 1024;
    const float* xb0 = x + (blockbase + wave * 16 + lrow) * 256 + g * 8;

    half8 a[8];
    floatx4 lo[8], hi[8];

#define SB()    __builtin_amdgcn_sched_barrier(0)
#define XLD(i, xn) do { const float* p_ = (xn) + (i) * 32;                     \
                     lo[i] = *reinterpret_cast<const floatx4*>(p_);            \
                     hi[i] = *reinterpret_cast<const floatx4*>(p_ + 4); } while (0)
#define XLD_ALL(xn) do { XLD(0,xn); XLD(1,xn); XLD(2,xn); XLD(3,xn);           \
                         XLD(4,xn); XLD(5,xn); XLD(6,xn); XLD(7,xn); } while (0)
#define XCVT(i) do { half8 f_;                                                 \
                     f_[0] = (_Float16)lo[i][0]; f_[1] = (_Float16)lo[i][1];   \
                     f_[2] = (_Float16)lo[i][2]; f_[3] = (_Float16)lo[i][3];   \
                     f_[4] = (_Float16)hi[i][0]; f_[5] = (_Float16)hi[i][1];   \
                     f_[6] = (_Float16)hi[i][2]; f_[7] = (_Float16)hi[i][3];   \
                     a[i] = f_; } while (0)
#define XCVT_ALL() do { XCVT(0); XCVT(1); XCVT(2); XCVT(3);                    \
                        XCVT(4); XCVT(5); XCVT(6); XCVT(7); } while (0)

    // Issue pass-0 x prefetch FIRST (starts the HBM stream), then stage W.
    XLD_ALL(xb0);
    SB();
    {
        const floatx4* src = reinterpret_cast<const floatx4*>(Wf);
        floatx4* dst = reinterpret_cast<floatx4*>(Wl);
#pragma unroll
        for (int i = 0; i < 16; ++i)
            dst[tid + i * 512] = src[tid + i * 512];
    }
    if (tid < 256) dkL[tid] = dk[tid];
    const float bs = bias[0];
    __syncthreads();   // the only barrier (drains prefetch too — it's pass-0 data)

    XCVT_ALL();
    SB();

    const half8* Wv = reinterpret_cast<const half8*>(Wl);

#pragma unroll 1
    for (int p = 0; p < 8; ++p) {
        // issue next pass's x loads; they stream during the n-loop
        if (p < 7) {
            const float* xn = xb0 + (p + 1) * (128 * 256);
            XLD_ALL(xn);
        }
        SB();

        float rp[4] = {0, 0, 0, 0};
#pragma unroll 1
        for (int n = 0; n < 16; ++n) {
            const float kv = dkL[n * 16 + lrow];           // LDS: no vmcnt wait
            const half8* Wn = Wv + n * 512 + lane;
            floatx4 c0 = {0, 0, 0, 0};
#pragma unroll
            for (int kk = 0; kk < 8; ++kk)
                c0 = __builtin_amdgcn_mfma_f32_16x16x32_f16(a[kk], Wn[kk * 64], c0, 0, 0, 0);
#pragma unroll
            for (int r = 0; r < 4; ++r)
                rp[r] += c0[r] * c0[r] * kv;
        }

        // convert prefetched x (a[] is dead after the n-loop; waits vmcnt here)
        if (p < 7) { XCVT_ALL(); }
        SB();

        // reduce over the 16 cols (lanes sharing g) and store
#pragma unroll
        for (int r = 0; r < 4; ++r) {
            float v = rp[r];
            v += __shfl_xor(v, 1);
            v += __shfl_xor(v, 2);
            v += __shfl_xor(v, 4);
            v += __shfl_xor(v, 8);
            rp[r] = v;
        }
        if (lrow == 0) {
            floatx4 o;
#pragma unroll
            for (int r = 0; r < 4; ++r) o[r] = rp[r] * WSCALE_INV + bs;
            *reinterpret_cast<floatx4*>(out + blockbase + p * 128 + wave * 16 + g * 4) = o;
        }
    }
}

extern "C" void kernel_launch(void* const* d_in, const int* in_sizes, int n_in,
                              void* d_out, int out_size, void* d_ws, size_t ws_size,
                              hipStream_t stream) {
    const float* x    = (const float*)d_in[0];
    const float* w    = (const float*)d_in[1];
    const float* dk   = (const float*)d_in[2];
    const float* bias = (const float*)d_in[3];
    float* out = (float*)d_out;
    float* ws  = (float*)d_ws;

    _Float16* Wf16 = (_Float16*)(ws + WF16_OFF);

    // Allow 129 KB dynamic LDS (host-side attribute; validated pattern in R5).
    static bool attr_set = false;
    if (!attr_set) {
        hipFuncSetAttribute((const void*)mpo_main,
                            hipFuncAttributeMaxDynamicSharedMemorySize, 132096);
        attr_set = true;
    }

    // Fused W contraction (one tiny single-block kernel)
    mpo_prep<<<1, 1024, 0, stream>>>(w, ws, Wf16);

    // Main fused GEMM + square + dot: 256 blocks x 512 threads, 129 KB LDS
    mpo_main<<<256, 512, 132096, stream>>>(x, Wf16, dk, bias, out);
}

// Round 7
// 74.254 us; speedup vs baseline: 2.9958x; 2.9958x over previous
//
#include <hip/hip_runtime.h>
#include <hip/hip_bf16.h>

typedef _Float16 half8 __attribute__((ext_vector_type(8)));
typedef float    floatx4 __attribute__((ext_vector_type(4)));

#define WSCALE      4096.0f
#define WSCALE_INV  (1.0f/(4096.0f*4096.0f))

// ws layout (float offsets). S-tensors live only in prep1's LDS now;
// global ws holds T1 and U for prep2.
#define T1_OFF   0      // 4096 floats (16,16,16)
#define U_OFF    4096   // 4096 floats (16,4,4,4,4)
#define WF16_OFF 8192   // 65536 _Float16, fragment-major; 16B-aligned

// ---- Prep 1: stages A (pair-contract) + B (T1) + U, one block, LDS-staged ----
// A: supercores S0..S3 from w (in LDS). B: T1[b,I4,J4] from S0,S1.
// U[a,kc,mc,k2,m2] = sum_b S2[a,b,kc,mc]*S3[b,k2,m2]  (pre-contraction that
// replaces the 1M-MAC T2 stage entirely).
__global__ __launch_bounds__(1024)
void mpo_prep1(const float* __restrict__ w, float* __restrict__ ws) {
    __shared__ float wL[6272];
    __shared__ float sL[8704];   // S0[0..255] S1[256..4351] S2[4352..8447] S3[8448..8703]
    const int tid = threadIdx.x;

    for (int i = tid; i < 6272; i += 1024) wL[i] = w[i];
    __syncthreads();

    // Stage A
    for (int idx = tid; idx < 8704; idx += 1024) {
        int p, base, r, outoff;
        if      (idx < 256)  { p = 0; base = 0;    r = 16; outoff = 0;    }
        else if (idx < 4352) { p = 1; base = 256;  r = 16; outoff = 256;  }
        else if (idx < 8448) { p = 2; base = 4352; r = 16; outoff = 4352; }
        else                 { p = 3; base = 8448; r = 1;  outoff = 8448; }
        int li = idx - base;
        int mm = li & 3, kk = (li >> 2) & 3, ac = li >> 4;
        int c = ac % r, a = ac / r;
        int k1 = kk >> 1, k2 = kk & 1, m1 = mm >> 1, m2 = mm & 1;
        const int coreoff[8] = {0, 64, 1088, 2112, 3136, 4160, 5184, 6208};
        const float* A = wL + coreoff[2 * p];       // (l,16,2,2)
        const float* B = wL + coreoff[2 * p + 1];   // (16,r,2,2)
        float s = 0.f;
        for (int b = 0; b < 16; ++b)
            s += A[((a * 16 + b) * 2 + k1) * 2 + m1] * B[((b * r + c) * 2 + k2) * 2 + m2];
        sL[outoff + li] = s;   // S[a][c][k1*2+k2][m1*2+m2]
    }
    __syncthreads();

    // Stage B: T1[(b*16+I4)*16+J4] = sum_a S0[a*16+I*4+J] * S1[((a*16+b)*4+k)*4+m]
    for (int idx = tid; idx < 4096; idx += 1024) {
        int J4 = idx & 15; int t = idx >> 4; int I4 = t & 15; int b = t >> 4;
        int I = I4 >> 2, k = I4 & 3, J = J4 >> 2, m = J4 & 3;
        float s = 0.f;
        for (int a = 0; a < 16; ++a)
            s += sL[a * 16 + I * 4 + J] * sL[256 + ((a * 16 + b) * 4 + k) * 4 + m];
        ws[T1_OFF + idx] = s;
    }

    // Stage U: U[(((a*4+kc)*4+mc)*4+k2)*4+m2] = sum_b S2[a,b,kc,mc]*S3[b,k2,m2]
    for (int idx = tid; idx < 4096; idx += 1024) {
        int m2 = idx & 3, k2 = (idx >> 2) & 3, mc = (idx >> 4) & 3,
            kc = (idx >> 6) & 3, a = idx >> 8;
        float s = 0.f;
        for (int b = 0; b < 16; ++b)
            s += sL[4352 + ((a * 16 + b) * 4 + kc) * 4 + mc] *
                 sL[8448 + (b * 4 + k2) * 4 + m2];
        ws[U_OFF + idx] = s;
    }
}

// ---- Prep 2: W[k=I4][col=J4] = sum_a T1[a,I16,J16]*U[a,kc,mc,k2,m2],
// scaled, fp16, FRAGMENT-MAJOR: strip n=col>>4, lrow=col&15, kk=k>>5,
// g=(k>>3)&3, j=k&7. 16 MACs/output; T1+U are L1-hot (32 KB).
__global__ __launch_bounds__(256)
void mpo_prep2(const float* __restrict__ ws, _Float16* __restrict__ Wf) {
    int idx = blockIdx.x * blockDim.x + threadIdx.x;   // 65536
    int J4 = idx & 255, I4 = idx >> 8;                 // col, k
    int I16 = I4 >> 4, kc = (I4 >> 2) & 3, k2 = I4 & 3;
    int J16 = J4 >> 4, mc = (J4 >> 2) & 3, m2 = J4 & 3;
    const float* T1 = ws + T1_OFF;
    const float* U  = ws + U_OFF + (((kc * 4 + mc) * 4 + k2) * 4 + m2);
    float s = 0.f;
#pragma unroll
    for (int a = 0; a < 16; ++a)
        s += T1[(a * 16 + I16) * 16 + J16] * U[a * 256];
    int n = J4 >> 4, lr = J4 & 15, kk = I4 >> 5, gg = (I4 >> 3) & 3, j = I4 & 7;
    Wf[(((n * 8 + kk) * 64) + gg * 16 + lr) * 8 + j] = (_Float16)(s * WSCALE);
}

// ---- Main fused kernel (unchanged from R6 — measured ~53.6 us) ----
// 256 blocks x 512 threads (8 waves, 2/SIMD, VGPR cap 256). All of W (128 KB)
// + dk (1 KB) in LDS; one barrier. 16 rows/wave x 8 passes with CROSS-PASS
// x prefetch; dk reads from LDS so the n-loop has NO vmcnt waits.
__global__ __launch_bounds__(512, 2)
void mpo_main(const float* __restrict__ x, const _Float16* __restrict__ Wf,
              const float* __restrict__ dk, const float* __restrict__ bias,
              float* __restrict__ out) {
    extern __shared__ _Float16 Wl[];                       // 65536 halves + 256 floats
    float* dkL = reinterpret_cast<float*>(Wl + 65536);

    const int tid  = threadIdx.x;
    const int lane = tid & 63;
    const int wave = tid >> 6;        // 0..7
    const int lrow = lane & 15;       // A row / C col within tile
    const int g    = lane >> 4;       // k-group

    const long blockbase = (long)blockIdx.x * 1024;
    const float* xb0 = x + (blockbase + wave * 16 + lrow) * 256 + g * 8;

    half8 a[8];
    floatx4 lo[8], hi[8];

#define SB()    __builtin_amdgcn_sched_barrier(0)
#define XLD(i, xn) do { const float* p_ = (xn) + (i) * 32;                     \
                     lo[i] = *reinterpret_cast<const floatx4*>(p_);            \
                     hi[i] = *reinterpret_cast<const floatx4*>(p_ + 4); } while (0)
#define XLD_ALL(xn) do { XLD(0,xn); XLD(1,xn); XLD(2,xn); XLD(3,xn);           \
                         XLD(4,xn); XLD(5,xn); XLD(6,xn); XLD(7,xn); } while (0)
#define XCVT(i) do { half8 f_;                                                 \
                     f_[0] = (_Float16)lo[i][0]; f_[1] = (_Float16)lo[i][1];   \
                     f_[2] = (_Float16)lo[i][2]; f_[3] = (_Float16)lo[i][3];   \
                     f_[4] = (_Float16)hi[i][0]; f_[5] = (_Float16)hi[i][1];   \
                     f_[6] = (_Float16)hi[i][2]; f_[7] = (_Float16)hi[i][3];   \
                     a[i] = f_; } while (0)
#define XCVT_ALL() do { XCVT(0); XCVT(1); XCVT(2); XCVT(3);                    \
                        XCVT(4); XCVT(5); XCVT(6); XCVT(7); } while (0)

    // Issue pass-0 x prefetch FIRST (starts the HBM stream), then stage W.
    XLD_ALL(xb0);
    SB();
    {
        const floatx4* src = reinterpret_cast<const floatx4*>(Wf);
        floatx4* dst = reinterpret_cast<floatx4*>(Wl);
#pragma unroll
        for (int i = 0; i < 16; ++i)
            dst[tid + i * 512] = src[tid + i * 512];
    }
    if (tid < 256) dkL[tid] = dk[tid];
    const float bs = bias[0];
    __syncthreads();   // the only barrier (drains prefetch too — it's pass-0 data)

    XCVT_ALL();
    SB();

    const half8* Wv = reinterpret_cast<const half8*>(Wl);

#pragma unroll 1
    for (int p = 0; p < 8; ++p) {
        // issue next pass's x loads; they stream during the n-loop
        if (p < 7) {
            const float* xn = xb0 + (p + 1) * (128 * 256);
            XLD_ALL(xn);
        }
        SB();

        float rp[4] = {0, 0, 0, 0};
#pragma unroll 1
        for (int n = 0; n < 16; ++n) {
            const float kv = dkL[n * 16 + lrow];           // LDS: no vmcnt wait
            const half8* Wn = Wv + n * 512 + lane;
            floatx4 c0 = {0, 0, 0, 0};
#pragma unroll
            for (int kk = 0; kk < 8; ++kk)
                c0 = __builtin_amdgcn_mfma_f32_16x16x32_f16(a[kk], Wn[kk * 64], c0, 0, 0, 0);
#pragma unroll
            for (int r = 0; r < 4; ++r)
                rp[r] += c0[r] * c0[r] * kv;
        }

        // convert prefetched x (a[] is dead after the n-loop; waits vmcnt here)
        if (p < 7) { XCVT_ALL(); }
        SB();

        // reduce over the 16 cols (lanes sharing g) and store
#pragma unroll
        for (int r = 0; r < 4; ++r) {
            float v = rp[r];
            v += __shfl_xor(v, 1);
            v += __shfl_xor(v, 2);
            v += __shfl_xor(v, 4);
            v += __shfl_xor(v, 8);
            rp[r] = v;
        }
        if (lrow == 0) {
            floatx4 o;
#pragma unroll
            for (int r = 0; r < 4; ++r) o[r] = rp[r] * WSCALE_INV + bs;
            *reinterpret_cast<floatx4*>(out + blockbase + p * 128 + wave * 16 + g * 4) = o;
        }
    }
}

extern "C" void kernel_launch(void* const* d_in, const int* in_sizes, int n_in,
                              void* d_out, int out_size, void* d_ws, size_t ws_size,
                              hipStream_t stream) {
    const float* x    = (const float*)d_in[0];
    const float* w    = (const float*)d_in[1];
    const float* dk   = (const float*)d_in[2];
    const float* bias = (const float*)d_in[3];
    float* out = (float*)d_out;
    float* ws  = (float*)d_ws;

    _Float16* Wf16 = (_Float16*)(ws + WF16_OFF);

    // Allow 129 KB dynamic LDS for mpo_main (host-side attr; validated R5/R6).
    static bool attr_set = false;
    if (!attr_set) {
        hipFuncSetAttribute((const void*)mpo_main,
                            hipFuncAttributeMaxDynamicSharedMemorySize, 132096);
        attr_set = true;
    }

    // W contraction: 2 tiny kernels (A+B+U fused in LDS, then W itself)
    mpo_prep1<<<1, 1024, 0, stream>>>(w, ws);
    mpo_prep2<<<256, 256, 0, stream>>>(ws, Wf16);

    // Main fused GEMM + square + dot: 256 blocks x 512 threads, 129 KB LDS
    mpo_main<<<256, 512, 132096, stream>>>(x, Wf16, dk, bias, out);
}

// Round 8
// 70.409 us; speedup vs baseline: 3.1594x; 1.0546x over previous
//
#include <hip/hip_runtime.h>
#include <hip/hip_bf16.h>

typedef _Float16 half8 __attribute__((ext_vector_type(8)));
typedef float    floatx4 __attribute__((ext_vector_type(4)));

#define WSCALE      4096.0f
#define WSCALE_INV  (1.0f/(4096.0f*4096.0f))

// ws layout (float offsets). S-tensors live only in prep1's LDS;
// global ws holds T1 and U for prep2.
#define T1_OFF   0      // 4096 floats (16,16,16)
#define U_OFF    4096   // 4096 floats (16,4,4,4,4)
#define WF16_OFF 8192   // 65536 _Float16, fragment-major; 16B-aligned

// ---- Prep 1: TWO INDEPENDENT blocks ----
// block 0: S0 (cores 0x1) + S1 (cores 2x3) in LDS -> T1 -> ws
// block 1: S2 (cores 4x5) + S3 (cores 6x7) in LDS -> U  -> ws
// (T1 and U chains share no data, so they parallelize perfectly.)
__global__ __launch_bounds__(1024)
void mpo_prep1(const float* __restrict__ w, float* __restrict__ ws) {
    __shared__ float wL[3136];
    __shared__ float sL[4352];
    const int tid = threadIdx.x;

    if (blockIdx.x == 0) {
        for (int i = tid; i < 3136; i += 1024) wL[i] = w[i];
        __syncthreads();
        // S0 = cores0x1: A (1,16,2,2) @0, B (16,16,2,2) @64 -> sL[0..256)
        if (tid < 256) {
            int li = tid;
            int mm = li & 3, kk = (li >> 2) & 3, c = li >> 4;
            int k1 = kk >> 1, k2 = kk & 1, m1 = mm >> 1, m2 = mm & 1;
            float s = 0.f;
            for (int b = 0; b < 16; ++b)
                s += wL[(b * 2 + k1) * 2 + m1] * wL[64 + ((b * 16 + c) * 2 + k2) * 2 + m2];
            sL[li] = s;
        }
        // S1 = cores2x3: A (16,16,2,2) @1088, B (16,16,2,2) @2112 -> sL[256..4352)
        for (int li = tid; li < 4096; li += 1024) {
            int mm = li & 3, kk = (li >> 2) & 3, ac = li >> 4;
            int c = ac & 15, a = ac >> 4;
            int k1 = kk >> 1, k2 = kk & 1, m1 = mm >> 1, m2 = mm & 1;
            float s = 0.f;
            for (int b = 0; b < 16; ++b)
                s += wL[1088 + ((a * 16 + b) * 2 + k1) * 2 + m1]
                   * wL[2112 + ((b * 16 + c) * 2 + k2) * 2 + m2];
            sL[256 + li] = s;
        }
        __syncthreads();
        // T1[(b*16+I4)*16+J4] = sum_a S0[a*16+I*4+J] * S1[((a*16+b)*4+k)*4+m]
        for (int idx = tid; idx < 4096; idx += 1024) {
            int J4 = idx & 15; int t = idx >> 4; int I4 = t & 15; int b = t >> 4;
            int I = I4 >> 2, k = I4 & 3, J = J4 >> 2, m = J4 & 3;
            float s = 0.f;
            for (int a = 0; a < 16; ++a)
                s += sL[a * 16 + I * 4 + J] * sL[256 + ((a * 16 + b) * 4 + k) * 4 + m];
            ws[T1_OFF + idx] = s;
        }
    } else {
        for (int i = tid; i < 3136; i += 1024) wL[i] = w[3136 + i];
        __syncthreads();
        // S2 = cores4x5: A (16,16,2,2) @0, B (16,16,2,2) @1024 -> sL[0..4096)
        for (int li = tid; li < 4096; li += 1024) {
            int mm = li & 3, kk = (li >> 2) & 3, ac = li >> 4;
            int c = ac & 15, a = ac >> 4;
            int k1 = kk >> 1, k2 = kk & 1, m1 = mm >> 1, m2 = mm & 1;
            float s = 0.f;
            for (int b = 0; b < 16; ++b)
                s += wL[((a * 16 + b) * 2 + k1) * 2 + m1]
                   * wL[1024 + ((b * 16 + c) * 2 + k2) * 2 + m2];
            sL[li] = s;
        }
        // S3 = cores6x7: A (16,16,2,2) @2048, B (16,1,2,2) @3072 -> sL[4096..4352)
        if (tid < 256) {
            int li = tid;
            int mm = li & 3, kk = (li >> 2) & 3, a = li >> 4;   // c = 0 (r=1)
            int k1 = kk >> 1, k2 = kk & 1, m1 = mm >> 1, m2 = mm & 1;
            float s = 0.f;
            for (int b = 0; b < 16; ++b)
                s += wL[2048 + ((a * 16 + b) * 2 + k1) * 2 + m1]
                   * wL[3072 + (b * 2 + k2) * 2 + m2];
            sL[4096 + li] = s;
        }
        __syncthreads();
        // U[(((a*4+kc)*4+mc)*4+k2)*4+m2] = sum_b S2[a,b,kc,mc]*S3[b,k2,m2]
        for (int idx = tid; idx < 4096; idx += 1024) {
            int m2 = idx & 3, k2 = (idx >> 2) & 3, mc = (idx >> 4) & 3,
                kc = (idx >> 6) & 3, a = idx >> 8;
            float s = 0.f;
            for (int b = 0; b < 16; ++b)
                s += sL[((a * 16 + b) * 4 + kc) * 4 + mc] * sL[4096 + (b * 4 + k2) * 4 + m2];
            ws[U_OFF + idx] = s;
        }
    }
}

// ---- Prep 2: W[k=I4][col=J4] = sum_a T1[a,I16,J16]*U[a,kc,mc,k2,m2],
// scaled, fp16, FRAGMENT-MAJOR: strip n=col>>4, lrow=col&15, kk=k>>5,
// g=(k>>3)&3, j=k&7. 16 MACs/output; T1+U are L2-hot (32 KB).
__global__ __launch_bounds__(256)
void mpo_prep2(const float* __restrict__ ws, _Float16* __restrict__ Wf) {
    int idx = blockIdx.x * blockDim.x + threadIdx.x;   // 65536
    int J4 = idx & 255, I4 = idx >> 8;                 // col, k
    int I16 = I4 >> 4, kc = (I4 >> 2) & 3, k2 = I4 & 3;
    int J16 = J4 >> 4, mc = (J4 >> 2) & 3, m2 = J4 & 3;
    const float* T1 = ws + T1_OFF;
    const float* U  = ws + U_OFF + (((kc * 4 + mc) * 4 + k2) * 4 + m2);
    float s = 0.f;
#pragma unroll
    for (int a = 0; a < 16; ++a)
        s += T1[(a * 16 + I16) * 16 + J16] * U[a * 256];
    int n = J4 >> 4, lr = J4 & 15, kk = I4 >> 5, gg = (I4 >> 3) & 3, j = I4 & 7;
    Wf[(((n * 8 + kk) * 64) + gg * 16 + lr) * 8 + j] = (_Float16)(s * WSCALE);
}

// ---- Main fused kernel (validated R6/R7 structure; x loads now nontemporal) ----
// 256 blocks x 512 threads (8 waves, 2/SIMD, VGPR cap 256). All of W (128 KB)
// + dk (1 KB) in LDS; one barrier. 16 rows/wave x 8 passes with CROSS-PASS
// x prefetch; dk reads from LDS so the n-loop has NO vmcnt waits.
__global__ __launch_bounds__(512, 2)
void mpo_main(const float* __restrict__ x, const _Float16* __restrict__ Wf,
              const float* __restrict__ dk, const float* __restrict__ bias,
              float* __restrict__ out) {
    extern __shared__ _Float16 Wl[];                       // 65536 halves + 256 floats
    float* dkL = reinterpret_cast<float*>(Wl + 65536);

    const int tid  = threadIdx.x;
    const int lane = tid & 63;
    const int wave = tid >> 6;        // 0..7
    const int lrow = lane & 15;       // A row / C col within tile
    const int g    = lane >> 4;       // k-group

    const long blockbase = (long)blockIdx.x * 1024;
    const float* xb0 = x + (blockbase + wave * 16 + lrow) * 256 + g * 8;

    half8 a[8];
    floatx4 lo[8], hi[8];

#define SB()    __builtin_amdgcn_sched_barrier(0)
#define XLD(i, xn) do { const float* p_ = (xn) + (i) * 32;                                  \
                     lo[i] = __builtin_nontemporal_load(reinterpret_cast<const floatx4*>(p_));     \
                     hi[i] = __builtin_nontemporal_load(reinterpret_cast<const floatx4*>(p_ + 4)); \
                   } while (0)
#define XLD_ALL(xn) do { XLD(0,xn); XLD(1,xn); XLD(2,xn); XLD(3,xn);           \
                         XLD(4,xn); XLD(5,xn); XLD(6,xn); XLD(7,xn); } while (0)
#define XCVT(i) do { half8 f_;                                                 \
                     f_[0] = (_Float16)lo[i][0]; f_[1] = (_Float16)lo[i][1];   \
                     f_[2] = (_Float16)lo[i][2]; f_[3] = (_Float16)lo[i][3];   \
                     f_[4] = (_Float16)hi[i][0]; f_[5] = (_Float16)hi[i][1];   \
                     f_[6] = (_Float16)hi[i][2]; f_[7] = (_Float16)hi[i][3];   \
                     a[i] = f_; } while (0)
#define XCVT_ALL() do { XCVT(0); XCVT(1); XCVT(2); XCVT(3);                    \
                        XCVT(4); XCVT(5); XCVT(6); XCVT(7); } while (0)

    // Issue pass-0 x prefetch FIRST (starts the HBM stream), then stage W.
    XLD_ALL(xb0);
    SB();
    {
        const floatx4* src = reinterpret_cast<const floatx4*>(Wf);
        floatx4* dst = reinterpret_cast<floatx4*>(Wl);
#pragma unroll
        for (int i = 0; i < 16; ++i)
            dst[tid + i * 512] = src[tid + i * 512];
    }
    if (tid < 256) dkL[tid] = dk[tid];
    const float bs = bias[0];
    __syncthreads();   // the only barrier (drains prefetch too — it's pass-0 data)

    XCVT_ALL();
    SB();

    const half8* Wv = reinterpret_cast<const half8*>(Wl);

#pragma unroll 1
    for (int p = 0; p < 8; ++p) {
        // issue next pass's x loads; they stream during the n-loop
        if (p < 7) {
            const float* xn = xb0 + (p + 1) * (128 * 256);
            XLD_ALL(xn);
        }
        SB();

        float rp[4] = {0, 0, 0, 0};
#pragma unroll 1
        for (int n = 0; n < 16; ++n) {
            const float kv = dkL[n * 16 + lrow];           // LDS: no vmcnt wait
            const half8* Wn = Wv + n * 512 + lane;
            floatx4 c0 = {0, 0, 0, 0};
#pragma unroll
            for (int kk = 0; kk < 8; ++kk)
                c0 = __builtin_amdgcn_mfma_f32_16x16x32_f16(a[kk], Wn[kk * 64], c0, 0, 0, 0);
#pragma unroll
            for (int r = 0; r < 4; ++r)
                rp[r] += c0[r] * c0[r] * kv;
        }

        // convert prefetched x (a[] is dead after the n-loop; waits vmcnt here)
        if (p < 7) { XCVT_ALL(); }
        SB();

        // reduce over the 16 cols (lanes sharing g) and store
#pragma unroll
        for (int r = 0; r < 4; ++r) {
            float v = rp[r];
            v += __shfl_xor(v, 1);
            v += __shfl_xor(v, 2);
            v += __shfl_xor(v, 4);
            v += __shfl_xor(v, 8);
            rp[r] = v;
        }
        if (lrow == 0) {
            floatx4 o;
#pragma unroll
            for (int r = 0; r < 4; ++r) o[r] = rp[r] * WSCALE_INV + bs;
            *reinterpret_cast<floatx4*>(out + blockbase + p * 128 + wave * 16 + g * 4) = o;
        }
    }
}

extern "C" void kernel_launch(void* const* d_in, const int* in_sizes, int n_in,
                              void* d_out, int out_size, void* d_ws, size_t ws_size,
                              hipStream_t stream) {
    const float* x    = (const float*)d_in[0];
    const float* w    = (const float*)d_in[1];
    const float* dk   = (const float*)d_in[2];
    const float* bias = (const float*)d_in[3];
    float* out = (float*)d_out;
    float* ws  = (float*)d_ws;

    _Float16* Wf16 = (_Float16*)(ws + WF16_OFF);

    // Allow 129 KB dynamic LDS for mpo_main (host-side attr; validated R5-R7).
    static bool attr_set = false;
    if (!attr_set) {
        hipFuncSetAttribute((const void*)mpo_main,
                            hipFuncAttributeMaxDynamicSharedMemorySize, 132096);
        attr_set = true;
    }

    // W contraction: prep1 (2 independent blocks: T1-chain, U-chain), then W
    mpo_prep1<<<2, 1024, 0, stream>>>(w, ws);
    mpo_prep2<<<256, 256, 0, stream>>>(ws, Wf16);

    // Main fused GEMM + square + dot: 256 blocks x 512 threads, 129 KB LDS
    mpo_main<<<256, 512, 132096, stream>>>(x, Wf16, dk, bias, out);
}